// Round 1
// baseline (1462.053 us; speedup 1.0000x reference)
//
#include <hip/hip_runtime.h>
#include <math.h>

#define BATCH 8
#define CHAN 256
#define NPIX 16384   // 128*128
#define KD 64
#define VD 64
#define HEADS 8
#define HDIM 512     // KD*HEADS

// ---------------- Kernel A: k/v projection ----------------
// k[b,d,n] = Wk[d,:]@x[b,:,n] + bk[d];  v[b,e,n] = Wv[e,:]@x[b,:,n] + bv[e]
// tile: 128 rows (64 k + 64 v) x 128 n, K=256 in chunks of 32. 8x8 per thread.
__global__ __launch_bounds__(256) void kv_proj(const float* __restrict__ x,
        const float* __restrict__ Wk, const float* __restrict__ bk,
        const float* __restrict__ Wv, const float* __restrict__ bv,
        float* __restrict__ kbuf, float* __restrict__ vbuf) {
    __shared__ float Wts[32][132];   // [c][row] transposed for vector reads
    __shared__ float Xs[32][128];    // [c][n]
    const int b = blockIdx.y;
    const int n0 = blockIdx.x * 128;
    const int tid = threadIdx.x;
    const int tx = tid & 15, ty = tid >> 4;
    float acc[8][8];
#pragma unroll
    for (int i = 0; i < 8; i++)
#pragma unroll
        for (int j = 0; j < 8; j++) acc[i][j] = 0.f;

    for (int c0 = 0; c0 < CHAN; c0 += 32) {
        // stage W chunk: 128 rows x 32 c (transposed)
#pragma unroll
        for (int j = 0; j < 4; j++) {
            int f4 = tid + 256 * j;          // 0..1023
            int r = f4 >> 3;                 // 0..127
            int c4 = f4 & 7;
            const float* src = (r < 64) ? (Wk + (size_t)r * CHAN + c0 + c4 * 4)
                                        : (Wv + (size_t)(r - 64) * CHAN + c0 + c4 * 4);
            float4 w = *(const float4*)src;
            Wts[c4 * 4 + 0][r] = w.x; Wts[c4 * 4 + 1][r] = w.y;
            Wts[c4 * 4 + 2][r] = w.z; Wts[c4 * 4 + 3][r] = w.w;
        }
        // stage X chunk: 32 c x 128 n
#pragma unroll
        for (int j = 0; j < 4; j++) {
            int f4 = tid + 256 * j;          // 0..1023
            int r = f4 >> 5;                 // 0..31
            int c4 = f4 & 31;
            float4 v = *(const float4*)(x + ((size_t)(b * CHAN + c0 + r)) * NPIX + n0 + c4 * 4);
            *(float4*)&Xs[r][c4 * 4] = v;
        }
        __syncthreads();
#pragma unroll
        for (int kk = 0; kk < 32; kk++) {
            float4 a1 = *(const float4*)&Wts[kk][ty * 4];
            float4 a2 = *(const float4*)&Wts[kk][64 + ty * 4];
            float4 b1 = *(const float4*)&Xs[kk][tx * 4];
            float4 b2 = *(const float4*)&Xs[kk][64 + tx * 4];
            float av[8] = {a1.x, a1.y, a1.z, a1.w, a2.x, a2.y, a2.z, a2.w};
            float bw[8] = {b1.x, b1.y, b1.z, b1.w, b2.x, b2.y, b2.z, b2.w};
#pragma unroll
            for (int i = 0; i < 8; i++)
#pragma unroll
                for (int j = 0; j < 8; j++) acc[i][j] += av[i] * bw[j];
        }
        __syncthreads();
    }
    // rows i<4 -> k row ty*4+i ; i>=4 -> v row ty*4+(i-4)
#pragma unroll
    for (int i = 0; i < 8; i++) {
        int r = ty * 4 + (i & 3);
        float bias = (i < 4) ? bk[r] : bv[r];
        float* dst = (i < 4) ? (kbuf + ((size_t)(b * KD + r)) * NPIX)
                             : (vbuf + ((size_t)(b * VD + r)) * NPIX);
        float4 o1 = {acc[i][0] + bias, acc[i][1] + bias, acc[i][2] + bias, acc[i][3] + bias};
        float4 o2 = {acc[i][4] + bias, acc[i][5] + bias, acc[i][6] + bias, acc[i][7] + bias};
        *(float4*)(dst + n0 + tx * 4) = o1;
        *(float4*)(dst + n0 + 64 + tx * 4) = o2;
    }
}

// ---------------- Kernel B: per-(b,d) row max of k ----------------
__global__ __launch_bounds__(256) void kmax_kernel(const float* __restrict__ kbuf,
                                                   float* __restrict__ kmax) {
    const int bd = blockIdx.x;   // 0..511
    const float* row = kbuf + (size_t)bd * NPIX;
    const int tid = threadIdx.x;
    float m = -1e30f;
    for (int i = tid * 4; i < NPIX; i += 256 * 4) {
        float4 v = *(const float4*)(row + i);
        m = fmaxf(m, fmaxf(fmaxf(v.x, v.y), fmaxf(v.z, v.w)));
    }
#pragma unroll
    for (int off = 32; off; off >>= 1) m = fmaxf(m, __shfl_down(m, off, 64));
    __shared__ float sm[4];
    if ((tid & 63) == 0) sm[tid >> 6] = m;
    __syncthreads();
    if (tid == 0) kmax[bd] = fmaxf(fmaxf(sm[0], sm[1]), fmaxf(sm[2], sm[3]));
}

// ---------------- zero scratch (ws is poisoned 0xAA each launch) ----------------
__global__ void zero_kernel(float* __restrict__ p, int n) {
    int i = blockIdx.x * 256 + threadIdx.x;
    if (i < n) p[i] = 0.f;
}

// ---------------- Kernel C: ctx[b,d,e] += sum_n exp(k-max)*v ; gsum[b,d] += sum exp ----------------
// grid (32 n-chunks, 8 b); each block covers 512 n in 4 sub-chunks of 128.
__global__ __launch_bounds__(256) void ctx_kernel(const float* __restrict__ kbuf,
        const float* __restrict__ vbuf, const float* __restrict__ kmax,
        float* __restrict__ ctx, float* __restrict__ gsum) {
    __shared__ float Ks[64][129];
    __shared__ float Vs[64][129];
    __shared__ float psum[4][64];
    const int b = blockIdx.y;
    const int nbase = blockIdx.x * 512;
    const int tid = threadIdx.x;
    const int tx = tid & 15, ty = tid >> 4;
    const float myMax = kmax[b * KD + (tid & 63)];
    float acc[4][4] = {};
    float localSum = 0.f;

    for (int s = 0; s < 4; s++) {
        const int n0 = nbase + s * 128;
#pragma unroll
        for (int j = 0; j < 8; j++) {
            int f4 = tid + 256 * j;    // 0..2047
            int r = f4 >> 5;           // 0..63
            int c4 = f4 & 31;
            *(float4*)&Ks[r][c4 * 4] = *(const float4*)(kbuf + ((size_t)(b * KD + r)) * NPIX + n0 + c4 * 4);
            *(float4*)&Vs[r][c4 * 4] = *(const float4*)(vbuf + ((size_t)(b * VD + r)) * NPIX + n0 + c4 * 4);
        }
        __syncthreads();
        // phase 1: exp transform + per-row partial sums (all 256 threads)
        {
            int d = tid & 63, q = tid >> 6;
            float ps = 0.f;
#pragma unroll
            for (int i = 0; i < 32; i++) {
                int nn = q * 32 + i;
                float w = __expf(Ks[d][nn] - myMax);
                Ks[d][nn] = w;
                ps += w;
            }
            psum[q][d] = ps;
        }
        __syncthreads();
        if (tid < 64) localSum += psum[0][tid] + psum[1][tid] + psum[2][tid] + psum[3][tid];
        // phase 2: acc[d][e] += w[d,n]*v[e,n]
        for (int nn = 0; nn < 128; nn++) {
            float kv[4], vv[4];
#pragma unroll
            for (int i = 0; i < 4; i++) kv[i] = Ks[ty * 4 + i][nn];
#pragma unroll
            for (int j = 0; j < 4; j++) vv[j] = Vs[tx * 4 + j][nn];
#pragma unroll
            for (int i = 0; i < 4; i++)
#pragma unroll
                for (int j = 0; j < 4; j++) acc[i][j] += kv[i] * vv[j];
        }
        __syncthreads();
    }
#pragma unroll
    for (int i = 0; i < 4; i++)
#pragma unroll
        for (int j = 0; j < 4; j++)
            atomicAdd(&ctx[((size_t)(b * KD + ty * 4 + i)) * VD + tx * 4 + j], acc[i][j]);
    if (tid < 64) atomicAdd(&gsum[b * KD + tid], localSum);
}

// ---------------- Kernel D: fold Wout with normalized ctx ----------------
// M[b,o,h*64+d] = (sum_e Wout[o,h*64+e] * ctx[b,d,e]) / gsum[b,d]
__global__ __launch_bounds__(256) void foldM_kernel(const float* __restrict__ Wout,
        const float* __restrict__ ctx, const float* __restrict__ gsum,
        float* __restrict__ M) {
    const int b = blockIdx.x >> 8;
    const int o = blockIdx.x & 255;
    const int tid = threadIdx.x;
#pragma unroll
    for (int rep = 0; rep < 2; rep++) {
        int hd = rep * 256 + tid;
        int h = hd >> 6, d = hd & 63;
        const float* wrow = Wout + (size_t)o * HDIM + h * 64;
        const float* crow = ctx + ((size_t)(b * KD + d)) * VD;
        float s = 0.f;
#pragma unroll 16
        for (int e = 0; e < 64; e++) s += wrow[e] * crow[e];
        M[((size_t)(b * CHAN) + o) * HDIM + hd] = s / gsum[b * KD + d];
    }
}

// ---------------- Kernel E: Q projection + per-head softmax over d ----------------
// one batch; block = (head h, 128-col n tile); tile 64 rows x 128 cols, K=256
__global__ __launch_bounds__(256) void qsoftmax_kernel(const float* __restrict__ x,
        const float* __restrict__ Wq, const float* __restrict__ bq,
        float* __restrict__ P, int b) {
    __shared__ float lds[8448];                       // 33 KB union
    float (*Wts)[72] = (float (*)[72])lds;            // 32*72   = 2304 f
    float (*Xs)[128] = (float (*)[128])(lds + 2304);  // 32*128  = 4096 f
    float (*S)[132]  = (float (*)[132])lds;           // 64*132  = 8448 f (after GEMM)
    const int h = blockIdx.y;
    const int n0 = blockIdx.x * 128;
    const int tid = threadIdx.x;
    const int tx = tid & 15, ty = tid >> 4;
    float acc[4][8] = {};

    for (int c0 = 0; c0 < CHAN; c0 += 32) {
#pragma unroll
        for (int j = 0; j < 2; j++) {
            int f4 = tid + 256 * j;     // 0..511
            int r = f4 >> 3;            // 0..63
            int c4 = f4 & 7;
            float4 w = *(const float4*)(Wq + ((size_t)(h * 64 + r)) * CHAN + c0 + c4 * 4);
            Wts[c4 * 4 + 0][r] = w.x; Wts[c4 * 4 + 1][r] = w.y;
            Wts[c4 * 4 + 2][r] = w.z; Wts[c4 * 4 + 3][r] = w.w;
        }
#pragma unroll
        for (int j = 0; j < 4; j++) {
            int f4 = tid + 256 * j;
            int r = f4 >> 5, c4 = f4 & 31;
            *(float4*)&Xs[r][c4 * 4] = *(const float4*)(x + ((size_t)(b * CHAN + c0 + r)) * NPIX + n0 + c4 * 4);
        }
        __syncthreads();
#pragma unroll
        for (int kk = 0; kk < 32; kk++) {
            float4 a1 = *(const float4*)&Wts[kk][ty * 4];
            float4 b1 = *(const float4*)&Xs[kk][tx * 4];
            float4 b2 = *(const float4*)&Xs[kk][64 + tx * 4];
            float av[4] = {a1.x, a1.y, a1.z, a1.w};
            float bw[8] = {b1.x, b1.y, b1.z, b1.w, b2.x, b2.y, b2.z, b2.w};
#pragma unroll
            for (int i = 0; i < 4; i++)
#pragma unroll
                for (int j = 0; j < 8; j++) acc[i][j] += av[i] * bw[j];
        }
        __syncthreads();
    }
    // bias + park scores in LDS (staging buffers are dead now)
#pragma unroll
    for (int i = 0; i < 4; i++) {
        int r = ty * 4 + i;
        float bias = bq[h * 64 + r];
#pragma unroll
        for (int j = 0; j < 8; j++) {
            int c = (j < 4) ? (tx * 4 + j) : (64 + tx * 4 + (j - 4));
            S[r][c] = acc[i][j] + bias;
        }
    }
    __syncthreads();
    // column softmax over the 64 rows of this head
    if (tid < 128) {
        const int c = tid;
        float m = -1e30f;
#pragma unroll 8
        for (int r = 0; r < 64; r++) m = fmaxf(m, S[r][c]);
        float s = 0.f;
#pragma unroll 8
        for (int r = 0; r < 64; r++) { float e = __expf(S[r][c] - m); S[r][c] = e; s += e; }
        float inv = 1.f / s;
#pragma unroll 8
        for (int r = 0; r < 64; r++)
            P[((size_t)(h * 64 + r)) * NPIX + n0 + c] = S[r][c] * inv;
    }
}

// ---------------- Kernel F: Y = M_b @ P + bout ----------------
// one batch; tile 64 rows(o) x 128 cols(n), K=512 in chunks of 32
__global__ __launch_bounds__(256) void ygemm_kernel(const float* __restrict__ M,
        const float* __restrict__ P, const float* __restrict__ bout,
        float* __restrict__ out, int b) {
    __shared__ float Mts[32][72];
    __shared__ float Ps[32][128];
    const int rt = blockIdx.y;          // 0..3
    const int n0 = blockIdx.x * 128;
    const int tid = threadIdx.x;
    const int tx = tid & 15, ty = tid >> 4;
    const float* Mb = M + (size_t)b * CHAN * HDIM;
    float acc[4][8] = {};

    for (int c0 = 0; c0 < HDIM; c0 += 32) {
#pragma unroll
        for (int j = 0; j < 2; j++) {
            int f4 = tid + 256 * j;     // 0..511
            int r = f4 >> 3, c4 = f4 & 7;
            float4 w = *(const float4*)(Mb + ((size_t)(rt * 64 + r)) * HDIM + c0 + c4 * 4);
            Mts[c4 * 4 + 0][r] = w.x; Mts[c4 * 4 + 1][r] = w.y;
            Mts[c4 * 4 + 2][r] = w.z; Mts[c4 * 4 + 3][r] = w.w;
        }
#pragma unroll
        for (int j = 0; j < 4; j++) {
            int f4 = tid + 256 * j;
            int r = f4 >> 5, c4 = f4 & 31;
            *(float4*)&Ps[r][c4 * 4] = *(const float4*)(P + ((size_t)(c0 + r)) * NPIX + n0 + c4 * 4);
        }
        __syncthreads();
#pragma unroll
        for (int kk = 0; kk < 32; kk++) {
            float4 a1 = *(const float4*)&Mts[kk][ty * 4];
            float4 b1 = *(const float4*)&Ps[kk][tx * 4];
            float4 b2 = *(const float4*)&Ps[kk][64 + tx * 4];
            float av[4] = {a1.x, a1.y, a1.z, a1.w};
            float bw[8] = {b1.x, b1.y, b1.z, b1.w, b2.x, b2.y, b2.z, b2.w};
#pragma unroll
            for (int i = 0; i < 4; i++)
#pragma unroll
                for (int j = 0; j < 8; j++) acc[i][j] += av[i] * bw[j];
        }
        __syncthreads();
    }
#pragma unroll
    for (int i = 0; i < 4; i++) {
        int o = rt * 64 + ty * 4 + i;
        float bias = bout[o];
        float4 o1 = {acc[i][0] + bias, acc[i][1] + bias, acc[i][2] + bias, acc[i][3] + bias};
        float4 o2 = {acc[i][4] + bias, acc[i][5] + bias, acc[i][6] + bias, acc[i][7] + bias};
        *(float4*)(out + ((size_t)(b * CHAN) + o) * NPIX + n0 + tx * 4) = o1;
        *(float4*)(out + ((size_t)(b * CHAN) + o) * NPIX + n0 + 64 + tx * 4) = o2;
    }
}

// ---------------- launch ----------------
extern "C" void kernel_launch(void* const* d_in, const int* in_sizes, int n_in,
                              void* d_out, int out_size, void* d_ws, size_t ws_size,
                              hipStream_t stream) {
    const float* x    = (const float*)d_in[0];
    const float* Wq   = (const float*)d_in[1];
    const float* bq   = (const float*)d_in[2];
    const float* Wk   = (const float*)d_in[3];
    const float* bk   = (const float*)d_in[4];
    const float* Wv   = (const float*)d_in[5];
    const float* bv   = (const float*)d_in[6];
    const float* Wout = (const float*)d_in[7];
    const float* bout = (const float*)d_in[8];
    float* out = (float*)d_out;
    float* ws  = (float*)d_ws;

    // ws layout (floats); total 17,859,584 f = 71.4 MB
    float* kbuf = ws;                  // 8*64*16384 = 8,388,608
    float* vbuf = ws + 8388608;        // 8,388,608
    float* kmax = ws + 16777216;       // 512
    float* gsum = ws + 16777728;       // 512
    float* ctx  = ws + 16778240;       // 8*64*64 = 32,768
    float* M    = ws + 16811008;       // 8*256*512 = 1,048,576
    float* P    = ws;                  // per-batch P[512][16384] aliases dead kbuf

    kv_proj<<<dim3(128, 8), 256, 0, stream>>>(x, Wk, bk, Wv, bv, kbuf, vbuf);
    kmax_kernel<<<dim3(512), 256, 0, stream>>>(kbuf, kmax);
    zero_kernel<<<dim3(130), 256, 0, stream>>>(gsum, 512 + 32768);   // gsum+ctx contiguous
    ctx_kernel<<<dim3(32, 8), 256, 0, stream>>>(kbuf, vbuf, kmax, ctx, gsum);
    foldM_kernel<<<dim3(2048), 256, 0, stream>>>(Wout, ctx, gsum, M);
    for (int b = 0; b < BATCH; b++) {
        qsoftmax_kernel<<<dim3(128, 8), 256, 0, stream>>>(x, Wq, bq, P, b);
        ygemm_kernel<<<dim3(128, 4), 256, 0, stream>>>(M, P, bout, out, b);
    }
}

// Round 2
// 554.269 us; speedup vs baseline: 2.6378x; 2.6378x over previous
//
#include <hip/hip_runtime.h>
#include <math.h>

#define BATCH 8
#define CHAN 256
#define NPIX 16384
#define KD 64
#define VD 64
#define HEADS 8
#define HDIM 512

typedef unsigned short u16;
typedef __bf16 bf16x8 __attribute__((ext_vector_type(8)));
typedef float f32x4 __attribute__((ext_vector_type(4)));

__device__ __forceinline__ u16 f2b(float f) {          // RNE fp32->bf16
    unsigned u = __float_as_uint(f);
    return (u16)((u + 0x7FFFu + ((u >> 16) & 1u)) >> 16);
}

// ---------- convert weights: Wq -> bf16 [512][256]; Wk|Wv -> Wkvb bf16 [128][256] ----------
__global__ __launch_bounds__(256) void cvt_w(const float* __restrict__ Wq,
        const float* __restrict__ Wk, const float* __restrict__ Wv,
        u16* __restrict__ Wqb, u16* __restrict__ Wkvb) {
    int idx = blockIdx.x * 256 + threadIdx.x;
    if (idx < 512 * 256) {
        Wqb[idx] = f2b(Wq[idx]);
    } else {
        int j = idx - 512 * 256;           // 0..32767
        int r = j >> 8, c = j & 255;
        Wkvb[j] = f2b(r < 64 ? Wk[r * 256 + c] : Wv[(r - 64) * 256 + c]);
    }
}

// ---------- x [b][c][n] fp32 -> xT [b][n][c] bf16 (64x64 LDS tile transpose) ----------
__global__ __launch_bounds__(256) void cvt_x(const float* __restrict__ x, u16* __restrict__ xT) {
    __shared__ u16 Tb[64][72];             // pitch 144B = 16*9 (aligned, bank-stride 4)
    const int bx = blockIdx.x;
    const int b = bx >> 10, cb = (bx >> 8) & 3, nb = bx & 255;
    const int c0 = cb * 64, n0 = nb * 64;
    const int tid = threadIdx.x;
    {
        const int r = tid >> 2, q = tid & 3;            // c-row, n-quarter
        const float* src = x + ((size_t)(b * CHAN) + c0 + r) * NPIX + n0 + q * 16;
#pragma unroll
        for (int i = 0; i < 4; i++) {
            float4 v = *(const float4*)(src + i * 4);
            Tb[q * 16 + i * 4 + 0][r] = f2b(v.x);
            Tb[q * 16 + i * 4 + 1][r] = f2b(v.y);
            Tb[q * 16 + i * 4 + 2][r] = f2b(v.z);
            Tb[q * 16 + i * 4 + 3][r] = f2b(v.w);
        }
    }
    __syncthreads();
    {
        const int n = tid >> 2, q = tid & 3;
        u16* dst = xT + ((size_t)(b * NPIX) + n0 + n) * CHAN + c0 + q * 16;
        *(uint4*)(dst)     = *(const uint4*)&Tb[n][q * 16];
        *(uint4*)(dst + 8) = *(const uint4*)&Tb[n][q * 16 + 8];
    }
}

// ---------- k/v projection via MFMA: [128 rows kv][128 n] tile, K=256 ----------
__global__ __launch_bounds__(256) void kv_mfma(const u16* __restrict__ xT,
        const u16* __restrict__ Wkvb, const float* __restrict__ bk,
        const float* __restrict__ bv, u16* __restrict__ kbuf, u16* __restrict__ vbuf) {
    __shared__ u16 Xs[128][72];            // [n][c] bf16, pitch 144B
    const int b = blockIdx.y;
    const int n0 = blockIdx.x * 128;
    const int tid = threadIdx.x;
    const int w = tid >> 6, l = tid & 63, l15 = l & 15, g = l >> 4;
    const int wm = w >> 1, wn = w & 1;     // wm: k(0)/v(1), wn: n-half
    f32x4 acc[4][4];
#pragma unroll
    for (int i = 0; i < 4; i++)
#pragma unroll
        for (int j = 0; j < 4; j++) acc[i][j] = f32x4{0.f, 0.f, 0.f, 0.f};

    const u16* xTb = xT + ((size_t)b * NPIX + n0) * CHAN;
    const u16* Ww  = Wkvb + (size_t)(wm * 64) * CHAN;

    for (int c0 = 0; c0 < CHAN; c0 += 64) {
#pragma unroll
        for (int it = 0; it < 4; it++) {
            int r = (tid >> 3) + it * 32, cq = tid & 7;
            *(uint4*)&Xs[r][cq * 8] = *(const uint4*)&xTb[(size_t)r * CHAN + c0 + cq * 8];
        }
        __syncthreads();
#pragma unroll
        for (int kk = 0; kk < 2; kk++) {
            bf16x8 bf[4];
#pragma unroll
            for (int j = 0; j < 4; j++)
                bf[j] = *(const bf16x8*)&Xs[wn * 64 + l15 + 16 * j][kk * 32 + 8 * g];
#pragma unroll
            for (int i = 0; i < 4; i++) {
                bf16x8 af = *(const bf16x8*)&Ww[(size_t)(l15 + 16 * i) * CHAN + c0 + kk * 32 + 8 * g];
#pragma unroll
                for (int j = 0; j < 4; j++)
                    acc[i][j] = __builtin_amdgcn_mfma_f32_16x16x32_bf16(af, bf[j], acc[i][j], 0, 0, 0);
            }
        }
        __syncthreads();
    }
    const float* bias = (wm == 0) ? bk : bv;
    u16* dst = (wm == 0) ? kbuf : vbuf;
#pragma unroll
    for (int i = 0; i < 4; i++) {
        f32x4 b4 = *(const f32x4*)&bias[16 * i + 4 * g];
#pragma unroll
        for (int j = 0; j < 4; j++)
#pragma unroll
            for (int r = 0; r < 4; r++) {
                int row = 16 * i + 4 * g + r;
                dst[((size_t)(b * 64) + row) * NPIX + n0 + wn * 64 + 16 * j + l15] =
                    f2b(acc[i][j][r] + b4[r]);
            }
    }
}

// ---------- per-(b,d) row max of bf16 k ----------
__global__ __launch_bounds__(256) void kmax_kernel(const u16* __restrict__ kbuf,
                                                   float* __restrict__ kmax) {
    const int bd = blockIdx.x;
    const u16* row = kbuf + (size_t)bd * NPIX;
    const int tid = threadIdx.x;
    float m = -1e30f;
    for (int i = tid * 8; i < NPIX; i += 2048) {
        uint4 v = *(const uint4*)&row[i];
        const unsigned* pw = (const unsigned*)&v;
#pragma unroll
        for (int p = 0; p < 4; p++) {
            m = fmaxf(m, __uint_as_float(pw[p] << 16));
            m = fmaxf(m, __uint_as_float(pw[p] & 0xFFFF0000u));
        }
    }
#pragma unroll
    for (int off = 32; off; off >>= 1) m = fmaxf(m, __shfl_down(m, off, 64));
    __shared__ float sm[4];
    if ((tid & 63) == 0) sm[tid >> 6] = m;
    __syncthreads();
    if (tid == 0) kmax[bd] = fmaxf(fmaxf(sm[0], sm[1]), fmaxf(sm[2], sm[3]));
}

__global__ void zero_kernel(float* __restrict__ p, int n) {
    int i = blockIdx.x * 256 + threadIdx.x;
    if (i < n) p[i] = 0.f;
}

// ---------- ctx[b,d,e] += sum_n exp(k-max)*v ; gsum[b,d] += sum exp ----------
__global__ __launch_bounds__(256) void ctx_kernel(const u16* __restrict__ kbuf,
        const u16* __restrict__ vbuf, const float* __restrict__ kmax,
        float* __restrict__ ctx, float* __restrict__ gsum) {
    __shared__ float Ks[128][68];          // [n][d], pitch 272B = 16*17
    __shared__ float Vs[128][68];
    __shared__ float psum[4][64];
    const int b = blockIdx.y;
    const int nbase = blockIdx.x * 512;
    const int tid = threadIdx.x;
    const int tx = tid & 15, ty = tid >> 4;
    const int lane = tid & 63, wq = tid >> 6;
    const float myMax = kmax[b * KD + lane];
    float acc[4][4] = {};
    float localSum = 0.f;

    for (int s = 0; s < 4; s++) {
        const int n0 = nbase + s * 128;
#pragma unroll
        for (int it = 0; it < 4; it++) {
            int e8 = tid + 256 * it;
            int d = e8 >> 4, c8 = e8 & 15;
            uint4 kk4 = *(const uint4*)&kbuf[((size_t)(b * KD + d)) * NPIX + n0 + c8 * 8];
            uint4 vv4 = *(const uint4*)&vbuf[((size_t)(b * VD + d)) * NPIX + n0 + c8 * 8];
            const unsigned* kw = (const unsigned*)&kk4;
            const unsigned* vw = (const unsigned*)&vv4;
#pragma unroll
            for (int p = 0; p < 4; p++) {
                Ks[c8 * 8 + 2 * p    ][d] = __uint_as_float(kw[p] << 16);
                Ks[c8 * 8 + 2 * p + 1][d] = __uint_as_float(kw[p] & 0xFFFF0000u);
                Vs[c8 * 8 + 2 * p    ][d] = __uint_as_float(vw[p] << 16);
                Vs[c8 * 8 + 2 * p + 1][d] = __uint_as_float(vw[p] & 0xFFFF0000u);
            }
        }
        __syncthreads();
        {
            float ps = 0.f;
#pragma unroll
            for (int i2 = 0; i2 < 32; i2++) {
                int nn = wq * 32 + i2;
                float wv = __expf(Ks[nn][lane] - myMax);
                Ks[nn][lane] = wv;
                ps += wv;
            }
            psum[wq][lane] = ps;
        }
        __syncthreads();
        if (tid < 64) localSum += psum[0][tid] + psum[1][tid] + psum[2][tid] + psum[3][tid];
        for (int nn = 0; nn < 128; nn++) {
            f32x4 kv = *(const f32x4*)&Ks[nn][ty * 4];
            f32x4 vv = *(const f32x4*)&Vs[nn][tx * 4];
#pragma unroll
            for (int i = 0; i < 4; i++)
#pragma unroll
                for (int j = 0; j < 4; j++) acc[i][j] += kv[i] * vv[j];
        }
        __syncthreads();
    }
#pragma unroll
    for (int i = 0; i < 4; i++)
#pragma unroll
        for (int j = 0; j < 4; j++)
            atomicAdd(&ctx[((size_t)(b * KD + ty * 4 + i)) * VD + tx * 4 + j], acc[i][j]);
    if (tid < 64) atomicAdd(&gsum[b * KD + tid], localSum);
}

// ---------- M[b,o,h*64+d] = (sum_e Wout[o,h*64+e]*ctx[b,d,e]) / gsum[b,d] -> bf16 ----------
__global__ __launch_bounds__(256) void foldM_kernel(const float* __restrict__ Wout,
        const float* __restrict__ ctx, const float* __restrict__ gsum,
        u16* __restrict__ Mb) {
    const int b = blockIdx.x >> 8;
    const int o = blockIdx.x & 255;
    const int tid = threadIdx.x;
#pragma unroll
    for (int rep = 0; rep < 2; rep++) {
        int hd = rep * 256 + tid;
        int h = hd >> 6, d = hd & 63;
        const float* wrow = Wout + (size_t)o * HDIM + h * 64;
        const float* crow = ctx + ((size_t)(b * KD + d)) * VD;
        float s = 0.f;
#pragma unroll 16
        for (int e = 0; e < 64; e++) s += wrow[e] * crow[e];
        Mb[((size_t)(b * CHAN) + o) * HDIM + hd] = f2b(s / gsum[b * KD + d]);
    }
}

// ---------- fused: Q-proj (MFMA) + per-head softmax + Y = M @ P^T (MFMA) ----------
// block: 512 thr = 8 waves; covers all 512 q-rows x 64 n-cols; Q-phase wave = head.
__global__ __launch_bounds__(512) void qy_fused(const u16* __restrict__ xT,
        const u16* __restrict__ Wqb, const float* __restrict__ bq,
        const u16* __restrict__ Mb, const float* __restrict__ bout,
        float* __restrict__ out) {
    __shared__ u16 Xs[64][72];             // staging, pitch 144B
    __shared__ u16 PT[64][520];            // P^T [n][hd], pitch 1040B = 16*65 (bank-stride 4)
    const int b = blockIdx.y;
    const int n0 = blockIdx.x * 64;
    const int tid = threadIdx.x;
    const int w = tid >> 6;                // wave id == head in Q-phase
    const int l = tid & 63, l15 = l & 15, g = l >> 4;

    f32x4 acc[4][4];
#pragma unroll
    for (int i = 0; i < 4; i++)
#pragma unroll
        for (int j = 0; j < 4; j++) acc[i][j] = f32x4{0.f, 0.f, 0.f, 0.f};

    const u16* xTb = xT + ((size_t)b * NPIX + n0) * CHAN;
    const u16* Wqw = Wqb + (size_t)(w * 64) * CHAN;

    for (int c0 = 0; c0 < CHAN; c0 += 64) {
        {
            int r = tid >> 3, cq = tid & 7;
            *(uint4*)&Xs[r][cq * 8] = *(const uint4*)&xTb[(size_t)r * CHAN + c0 + cq * 8];
        }
        __syncthreads();
#pragma unroll
        for (int kk = 0; kk < 2; kk++) {
            bf16x8 bf[4];
#pragma unroll
            for (int j = 0; j < 4; j++)
                bf[j] = *(const bf16x8*)&Xs[l15 + 16 * j][kk * 32 + 8 * g];
#pragma unroll
            for (int i = 0; i < 4; i++) {
                bf16x8 af = *(const bf16x8*)&Wqw[(size_t)(l15 + 16 * i) * CHAN + c0 + kk * 32 + 8 * g];
#pragma unroll
                for (int j = 0; j < 4; j++)
                    acc[i][j] = __builtin_amdgcn_mfma_f32_16x16x32_bf16(af, bf[j], acc[i][j], 0, 0, 0);
            }
        }
        __syncthreads();
    }

    // bias + column softmax over this head's 64 rows (rows live at 16i+4g+r)
    float mx[4] = {-1e30f, -1e30f, -1e30f, -1e30f};
#pragma unroll
    for (int i = 0; i < 4; i++) {
        f32x4 bq4 = *(const f32x4*)&bq[w * 64 + 16 * i + 4 * g];
#pragma unroll
        for (int j = 0; j < 4; j++) {
            acc[i][j] += bq4;
#pragma unroll
            for (int r = 0; r < 4; r++) mx[j] = fmaxf(mx[j], acc[i][j][r]);
        }
    }
#pragma unroll
    for (int j = 0; j < 4; j++) {
        mx[j] = fmaxf(mx[j], __shfl_xor(mx[j], 16, 64));
        mx[j] = fmaxf(mx[j], __shfl_xor(mx[j], 32, 64));
    }
    float sm[4] = {0.f, 0.f, 0.f, 0.f};
#pragma unroll
    for (int i = 0; i < 4; i++)
#pragma unroll
        for (int j = 0; j < 4; j++)
#pragma unroll
            for (int r = 0; r < 4; r++) {
                float e = __expf(acc[i][j][r] - mx[j]);
                acc[i][j][r] = e;
                sm[j] += e;
            }
#pragma unroll
    for (int j = 0; j < 4; j++) {
        sm[j] += __shfl_xor(sm[j], 16, 64);
        sm[j] += __shfl_xor(sm[j], 32, 64);
        sm[j] = 1.f / sm[j];
    }
#pragma unroll
    for (int i = 0; i < 4; i++)
#pragma unroll
        for (int j = 0; j < 4; j++) {
            ushort4 pk;
            pk.x = f2b(acc[i][j][0] * sm[j]);
            pk.y = f2b(acc[i][j][1] * sm[j]);
            pk.z = f2b(acc[i][j][2] * sm[j]);
            pk.w = f2b(acc[i][j][3] * sm[j]);
            *(ushort4*)&PT[l15 + 16 * j][w * 64 + 16 * i + 4 * g] = pk;
        }
    __syncthreads();

    // Y phase: Y[256 o][64 n] = M_b[256][512] @ P^T, waves 4x2 (64o x 32n each)
    const int wm = w >> 1, wn = w & 1;
    const u16* Mw = Mb + ((size_t)b * CHAN + wm * 64) * HDIM;
    f32x4 yacc[4][2];
#pragma unroll
    for (int i = 0; i < 4; i++)
#pragma unroll
        for (int j = 0; j < 2; j++) yacc[i][j] = f32x4{0.f, 0.f, 0.f, 0.f};

#pragma unroll 4
    for (int h0 = 0; h0 < HDIM; h0 += 32) {
        bf16x8 pf[2];
#pragma unroll
        for (int j = 0; j < 2; j++)
            pf[j] = *(const bf16x8*)&PT[wn * 32 + l15 + 16 * j][h0 + 8 * g];
#pragma unroll
        for (int i = 0; i < 4; i++) {
            bf16x8 af = *(const bf16x8*)&Mw[(size_t)(l15 + 16 * i) * HDIM + h0 + 8 * g];
#pragma unroll
            for (int j = 0; j < 2; j++)
                yacc[i][j] = __builtin_amdgcn_mfma_f32_16x16x32_bf16(af, pf[j], yacc[i][j], 0, 0, 0);
        }
    }
#pragma unroll
    for (int i = 0; i < 4; i++) {
        f32x4 bo = *(const f32x4*)&bout[wm * 64 + 16 * i + 4 * g];
#pragma unroll
        for (int j = 0; j < 2; j++)
#pragma unroll
            for (int r = 0; r < 4; r++)
                out[((size_t)(b * CHAN) + wm * 64 + 16 * i + 4 * g + r) * NPIX +
                    n0 + wn * 32 + 16 * j + l15] = yacc[i][j][r] + bo[r];
    }
}

// ---------------- launch ----------------
extern "C" void kernel_launch(void* const* d_in, const int* in_sizes, int n_in,
                              void* d_out, int out_size, void* d_ws, size_t ws_size,
                              hipStream_t stream) {
    const float* x    = (const float*)d_in[0];
    const float* Wq   = (const float*)d_in[1];
    const float* bq   = (const float*)d_in[2];
    const float* Wk   = (const float*)d_in[3];
    const float* bk   = (const float*)d_in[4];
    const float* Wv   = (const float*)d_in[5];
    const float* bv   = (const float*)d_in[6];
    const float* Wout = (const float*)d_in[7];
    const float* bout = (const float*)d_in[8];
    float* out = (float*)d_out;
    float* ws  = (float*)d_ws;

    // ws layout (float-granular offsets); total 25,805,824 f = 103.2 MB
    u16*   kbuf = (u16*)ws;                       // 8*64*16384 bf16
    u16*   vbuf = (u16*)(ws + 4194304);           // 8*64*16384 bf16
    u16*   xTb  = (u16*)(ws + 8388608);           // 8*16384*256 bf16
    u16*   Wqb  = (u16*)(ws + 25165824);          // 512*256 bf16
    u16*   Wkvb = (u16*)(ws + 25231360);          // 128*256 bf16
    u16*   Mb   = (u16*)(ws + 25247744);          // 8*256*512 bf16
    float* kmax = ws + 25772032;                  // 512
    float* gsum = ws + 25772544;                  // 512
    float* ctx  = ws + 25773056;                  // 32768

    cvt_w<<<dim3(640), 256, 0, stream>>>(Wq, Wk, Wv, Wqb, Wkvb);
    cvt_x<<<dim3(8192), 256, 0, stream>>>(x, xTb);
    kv_mfma<<<dim3(128, 8), 256, 0, stream>>>(xTb, Wkvb, bk, bv, kbuf, vbuf);
    kmax_kernel<<<dim3(512), 256, 0, stream>>>(kbuf, kmax);
    zero_kernel<<<dim3(130), 256, 0, stream>>>(gsum, 512 + 32768);
    ctx_kernel<<<dim3(32, 8), 256, 0, stream>>>(kbuf, vbuf, kmax, ctx, gsum);
    foldM_kernel<<<dim3(2048), 256, 0, stream>>>(Wout, ctx, gsum, Mb);
    qy_fused<<<dim3(256, 8), 512, 0, stream>>>(xTb, Wqb, bq, Mb, bout, out);
}